// Round 2
// baseline (3429.812 us; speedup 1.0000x reference)
//
#include <hip/hip_runtime.h>

#define N_TOKENS 131072
#define DIM 64
#define N_EMBED 1024
#define DECAYF 0.99f
#define OMDF 0.01f
#define EPSF 1e-5f
#define CHUNK 128

// Output layout (floats), reference return order:
// quantize_st [131072*64], diff [1], embed_ind [131072], new_embed [64*1024],
// new_cluster_size [1024], new_embed_avg [64*1024]
#define OFF_QST  ((size_t)0)
#define OFF_DIFF ((size_t)8388608)
#define OFF_IND  ((size_t)8388609)
#define OFF_NE   ((size_t)8519681)
#define OFF_NCS  ((size_t)8585217)
#define OFF_NEA  ((size_t)8586241)

// ws layout (floats):
// [0] diff_sum, [1] n_val, [2..1026) counts,
// [1026..66562) es[e*64+d], [66562..132098) embedT[e*64+d], [132098..133122) cnorm
#define WS_DIFF   0
#define WS_NVAL   1
#define WS_COUNTS 2
#define WS_ES     1026
#define WS_ET     66562
#define WS_CNORM  132098

__global__ __launch_bounds__(256) void vq_prep_transpose(
    const float* __restrict__ embed, float* __restrict__ embedT)
{
    int i = blockIdx.x * 256 + threadIdx.x;        // 65536 elems, coalesced read
    int d = i >> 10, e = i & 1023;
    embedT[e * DIM + d] = embed[i];
}

__global__ __launch_bounds__(256) void vq_prep_norm(
    const float* __restrict__ embedT, float* __restrict__ cnorm)
{
    int e = blockIdx.x * 256 + threadIdx.x;        // 1024
    const float4* c = (const float4*)(embedT + (size_t)e * DIM);
    float s = 0.f;
#pragma unroll
    for (int i = 0; i < 16; ++i) {
        float4 v = c[i];
        s = fmaf(v.x, v.x, s); s = fmaf(v.y, v.y, s);
        s = fmaf(v.z, v.z, s); s = fmaf(v.w, v.w, s);
    }
    cnorm[e] = s;
}

// T=2 tokens/thread, embed chunk staged in LDS.
// block b covers tokens [b*512, b*512+512); thread t owns b*512+t and b*512+256+t.
__global__ __launch_bounds__(256, 1) void vq_main(
    const float* __restrict__ x, const float* __restrict__ embedT,
    const float* __restrict__ cnorm, float* __restrict__ out,
    float* __restrict__ counts, float* __restrict__ es,
    float* __restrict__ diff_sum)
{
    __shared__ float ec[CHUNK * DIM];   // 32 KB: chunk of codes, [code][d]
    __shared__ float cnc[CHUNK];        // chunk code norms
    __shared__ float lcnt[N_EMBED];     // block histogram

    const int t = threadIdx.x;
    for (int i = t; i < N_EMBED; i += 256) lcnt[i] = 0.f;

    const size_t n0 = (size_t)blockIdx.x * 512 + t;
    const size_t n1 = n0 + 256;
    float4 xa[16], xb[16];
    {
        const float4* xv0 = (const float4*)(x + n0 * DIM);
        const float4* xv1 = (const float4*)(x + n1 * DIM);
#pragma unroll
        for (int i = 0; i < 16; ++i) { xa[i] = xv0[i]; xb[i] = xv1[i]; }
    }

    float best0 = 3.4e38f, best1 = 3.4e38f;
    int bi0 = 0, bi1 = 0;

    for (int c = 0; c < N_EMBED; c += CHUNK) {
        __syncthreads();                               // previous chunk fully consumed
        {   // stage CHUNK*64 floats = 2048 float4; 256 threads x 8 each; linear -> conflict-free
            const float4* src = (const float4*)(embedT + (size_t)c * DIM);
            float4* dst = (float4*)ec;
#pragma unroll
            for (int j = 0; j < (CHUNK * DIM / 4) / 256; ++j)
                dst[j * 256 + t] = src[j * 256 + t];
            if (t < CHUNK) cnc[t] = cnorm[c + t];
        }
        __syncthreads();

#pragma unroll 2
        for (int e = 0; e < CHUNK; ++e) {
            const float4* ev4 = (const float4*)(ec + e * DIM);
            float a0 = 0.f, a1 = 0.f, a2 = 0.f, a3 = 0.f;
            float b0 = 0.f, b1 = 0.f, b2 = 0.f, b3 = 0.f;
#pragma unroll
            for (int i = 0; i < 16; ++i) {
                float4 ev = ev4[i];                    // wave-uniform addr -> LDS broadcast
                a0 = fmaf(xa[i].x, ev.x, a0);
                a1 = fmaf(xa[i].y, ev.y, a1);
                a2 = fmaf(xa[i].z, ev.z, a2);
                a3 = fmaf(xa[i].w, ev.w, a3);
                b0 = fmaf(xb[i].x, ev.x, b0);
                b1 = fmaf(xb[i].y, ev.y, b1);
                b2 = fmaf(xb[i].z, ev.z, b2);
                b3 = fmaf(xb[i].w, ev.w, b3);
            }
            float cn = cnc[e];
            float dist0 = fmaf(-2.f, (a0 + a1) + (a2 + a3), cn);
            float dist1 = fmaf(-2.f, (b0 + b1) + (b2 + b3), cn);
            if (dist0 < best0) { best0 = dist0; bi0 = c + e; }   // strict <: first-index ties
            if (dist1 < best1) { best1 = dist1; bi1 = c + e; }
        }
    }

    out[OFF_IND + n0] = (float)bi0;
    out[OFF_IND + n1] = (float)bi1;
    atomicAdd(&lcnt[bi0], 1.f);
    atomicAdd(&lcnt[bi1], 1.f);

    // epilogue: quantize (== selected code), diff partials, es atomics
    float ds = 0.f;
    {
        const float4* qcol = (const float4*)(embedT + (size_t)bi0 * DIM);
        float4* qout = (float4*)(out + OFF_QST + n0 * DIM);
        float* esc = es + (size_t)bi0 * DIM;
#pragma unroll
        for (int i = 0; i < 16; ++i) {
            float4 q = qcol[i];
            float4 xx = xa[i];
            float ex = q.x - xx.x, ey = q.y - xx.y, ez = q.z - xx.z, ew = q.w - xx.w;
            qout[i] = q;                              // x + stopgrad(q - x) == q numerically
            ds = fmaf(ex, ex, ds); ds = fmaf(ey, ey, ds);
            ds = fmaf(ez, ez, ds); ds = fmaf(ew, ew, ds);
            atomicAdd(&esc[4 * i + 0], xx.x);
            atomicAdd(&esc[4 * i + 1], xx.y);
            atomicAdd(&esc[4 * i + 2], xx.z);
            atomicAdd(&esc[4 * i + 3], xx.w);
        }
    }
    {
        const float4* qcol = (const float4*)(embedT + (size_t)bi1 * DIM);
        float4* qout = (float4*)(out + OFF_QST + n1 * DIM);
        float* esc = es + (size_t)bi1 * DIM;
#pragma unroll
        for (int i = 0; i < 16; ++i) {
            float4 q = qcol[i];
            float4 xx = xb[i];
            float ex = q.x - xx.x, ey = q.y - xx.y, ez = q.z - xx.z, ew = q.w - xx.w;
            qout[i] = q;
            ds = fmaf(ex, ex, ds); ds = fmaf(ey, ey, ds);
            ds = fmaf(ez, ez, ds); ds = fmaf(ew, ew, ds);
            atomicAdd(&esc[4 * i + 0], xx.x);
            atomicAdd(&esc[4 * i + 1], xx.y);
            atomicAdd(&esc[4 * i + 2], xx.z);
            atomicAdd(&esc[4 * i + 3], xx.w);
        }
    }

    // diff: wave reduce, one atomic per wave
#pragma unroll
    for (int o = 32; o > 0; o >>= 1) ds += __shfl_down(ds, o, 64);
    if ((t & 63) == 0) atomicAdd(diff_sum, ds);

    // flush LDS histogram
    __syncthreads();
    for (int i = t; i < N_EMBED; i += 256) {
        float cval = lcnt[i];
        if (cval != 0.f) atomicAdd(&counts[i], cval);
    }
}

__global__ __launch_bounds__(1024) void vq_final1(
    const float* __restrict__ cluster_size, const float* __restrict__ counts,
    const float* __restrict__ diff_sum, float* __restrict__ out,
    float* __restrict__ n_val)
{
    int e = threadIdx.x;                            // single block of 1024
    float ncs = cluster_size[e] * DECAYF + OMDF * counts[e];
    out[OFF_NCS + e] = ncs;
    __shared__ float red[16];
    float s = ncs;
#pragma unroll
    for (int o = 32; o > 0; o >>= 1) s += __shfl_down(s, o, 64);
    if ((e & 63) == 0) red[e >> 6] = s;
    __syncthreads();
    if (e == 0) {
        float nsum = 0.f;
#pragma unroll
        for (int i = 0; i < 16; ++i) nsum += red[i];
        *n_val = nsum;
        out[OFF_DIFF] = *diff_sum / (float)((size_t)N_TOKENS * DIM);
    }
}

__global__ __launch_bounds__(256) void vq_final2(
    const float* __restrict__ embed_avg, const float* __restrict__ es,
    const float* __restrict__ n_val, float* __restrict__ out)
{
    int i = blockIdx.x * 256 + threadIdx.x;         // 65536, [d][e] flat
    int e = i & 1023, d = i >> 10;
    float nea = embed_avg[i] * DECAYF + OMDF * es[(size_t)e * DIM + d];
    out[OFF_NEA + i] = nea;
    float ncs = out[OFF_NCS + e];
    float nsum = *n_val;
    float cs = (ncs + EPSF) / (nsum + (float)N_EMBED * EPSF) * nsum;
    out[OFF_NE + i] = nea / cs;
}

extern "C" void kernel_launch(void* const* d_in, const int* in_sizes, int n_in,
                              void* d_out, int out_size, void* d_ws, size_t ws_size,
                              hipStream_t stream)
{
    const float* x            = (const float*)d_in[0];
    const float* embed        = (const float*)d_in[1];
    const float* cluster_size = (const float*)d_in[2];
    const float* embed_avg    = (const float*)d_in[3];
    float* out = (float*)d_out;
    float* ws  = (float*)d_ws;

    float* diff_sum = ws + WS_DIFF;
    float* n_val    = ws + WS_NVAL;
    float* counts   = ws + WS_COUNTS;
    float* es       = ws + WS_ES;
    float* embedT   = ws + WS_ET;
    float* cnorm    = ws + WS_CNORM;

    // zero accumulators: diff_sum, n_val, counts, es
    hipMemsetAsync(d_ws, 0, (size_t)WS_ET * sizeof(float), stream);

    vq_prep_transpose<<<256, 256, 0, stream>>>(embed, embedT);
    vq_prep_norm<<<4, 256, 0, stream>>>(embedT, cnorm);
    vq_main<<<N_TOKENS / 512, 256, 0, stream>>>(x, embedT, cnorm, out, counts, es, diff_sum);
    vq_final1<<<1, 1024, 0, stream>>>(cluster_size, counts, diff_sum, out, n_val);
    vq_final2<<<256, 256, 0, stream>>>(embed_avg, es, n_val, out);
}

// Round 3
// 1036.586 us; speedup vs baseline: 3.3088x; 3.3088x over previous
//
#include <hip/hip_runtime.h>

#define N_TOKENS 131072
#define DIM 64
#define N_EMBED 1024
#define DECAYF 0.99f
#define OMDF 0.01f
#define EPSF 1e-5f
#define CHUNK 128
#define SCAN_CHUNK 4096

// Output layout (floats), reference return order:
// quantize_st [131072*64], diff [1], embed_ind [131072], new_embed [64*1024],
// new_cluster_size [1024], new_embed_avg [64*1024]
#define OFF_QST  ((size_t)0)
#define OFF_DIFF ((size_t)8388608)
#define OFF_IND  ((size_t)8388609)
#define OFF_NE   ((size_t)8519681)
#define OFF_NCS  ((size_t)8585217)
#define OFF_NEA  ((size_t)8586241)

// ws layout (floats):
// [0] diff_sum, [1] n_val, [2..1026) counts,
// [1026..66562) es[e*64+d], [66562..132098) embedT[e*64+d], [132098..133122) cnorm
#define WS_DIFF   0
#define WS_NVAL   1
#define WS_COUNTS 2
#define WS_ES     1026
#define WS_ET     66562
#define WS_CNORM  132098

__global__ __launch_bounds__(256) void vq_prep_transpose(
    const float* __restrict__ embed, float* __restrict__ embedT)
{
    int i = blockIdx.x * 256 + threadIdx.x;        // 65536 elems, coalesced read
    int d = i >> 10, e = i & 1023;
    embedT[e * DIM + d] = embed[i];
}

__global__ __launch_bounds__(256) void vq_prep_norm(
    const float* __restrict__ embedT, float* __restrict__ cnorm)
{
    int e = blockIdx.x * 256 + threadIdx.x;        // 1024
    const float4* c = (const float4*)(embedT + (size_t)e * DIM);
    float s = 0.f;
#pragma unroll
    for (int i = 0; i < 16; ++i) {
        float4 v = c[i];
        s = fmaf(v.x, v.x, s); s = fmaf(v.y, v.y, s);
        s = fmaf(v.z, v.z, s); s = fmaf(v.w, v.w, s);
    }
    cnorm[e] = s;
}

// T=1 token/thread, 512 blocks (2/CU), embed chunk staged in LDS.
// NO global atomics in this kernel except 1 diff atomic per wave.
__global__ __launch_bounds__(256) void vq_main(
    const float* __restrict__ x, const float* __restrict__ embedT,
    const float* __restrict__ cnorm, float* __restrict__ out,
    float* __restrict__ diff_sum)
{
    __shared__ float ec[CHUNK * DIM];   // 32 KB: chunk of codes, [code][d]
    __shared__ float cnc[CHUNK];        // chunk code norms

    const int t = threadIdx.x;
    const size_t n = (size_t)blockIdx.x * 256 + t;   // one token per thread
    float4 xq[16];
    {
        const float4* xv = (const float4*)(x + n * DIM);
#pragma unroll
        for (int i = 0; i < 16; ++i) xq[i] = xv[i];
    }

    float best = 3.4e38f;
    int bi = 0;

    for (int c = 0; c < N_EMBED; c += CHUNK) {
        __syncthreads();                               // previous chunk fully consumed
        {   // stage CHUNK*64 floats = 2048 float4; 256 threads x 8 each
            const float4* src = (const float4*)(embedT + (size_t)c * DIM);
            float4* dst = (float4*)ec;
#pragma unroll
            for (int j = 0; j < (CHUNK * DIM / 4) / 256; ++j)
                dst[j * 256 + t] = src[j * 256 + t];
            if (t < CHUNK) cnc[t] = cnorm[c + t];
        }
        __syncthreads();

#pragma unroll 2
        for (int e = 0; e < CHUNK; ++e) {
            const float4* ev4 = (const float4*)(ec + e * DIM);
            float a0 = 0.f, a1 = 0.f, a2 = 0.f, a3 = 0.f;
#pragma unroll
            for (int i = 0; i < 16; ++i) {
                float4 ev = ev4[i];                    // wave-uniform addr -> LDS broadcast
                a0 = fmaf(xq[i].x, ev.x, a0);
                a1 = fmaf(xq[i].y, ev.y, a1);
                a2 = fmaf(xq[i].z, ev.z, a2);
                a3 = fmaf(xq[i].w, ev.w, a3);
            }
            float dist = fmaf(-2.f, (a0 + a1) + (a2 + a3), cnc[e]);
            if (dist < best) { best = dist; bi = c + e; }   // strict <: first-index ties
        }
    }

    out[OFF_IND + n] = (float)bi;

    // epilogue: quantize (== selected code), diff partial. NO es/counts atomics.
    float ds = 0.f;
    {
        const float4* qcol = (const float4*)(embedT + (size_t)bi * DIM);
        float4* qout = (float4*)(out + OFF_QST + n * DIM);
#pragma unroll
        for (int i = 0; i < 16; ++i) {
            float4 q = qcol[i];
            float4 xx = xq[i];
            float ex = q.x - xx.x, ey = q.y - xx.y, ez = q.z - xx.z, ew = q.w - xx.w;
            qout[i] = q;                              // x + stopgrad(q - x) == q numerically
            ds = fmaf(ex, ex, ds); ds = fmaf(ey, ey, ds);
            ds = fmaf(ez, ez, ds); ds = fmaf(ew, ew, ds);
        }
    }
#pragma unroll
    for (int o = 32; o > 0; o >>= 1) ds += __shfl_down(ds, o, 64);
    if ((t & 63) == 0) atomicAdd(diff_sum, ds);       // 2048 atomics total: negligible
}

// Phase 2: one block per code; scan embed_ind, gather matching x rows,
// write counts[e] and es[e][:] with exclusive ownership (zero atomics).
__global__ __launch_bounds__(256) void vq_scatter(
    const float* __restrict__ x, const float* __restrict__ out,
    float* __restrict__ counts, float* __restrict__ es)
{
    const int e = blockIdx.x;           // one code per block
    const int t = threadIdx.x;
    const float ef = (float)e;
    __shared__ int list[SCAN_CHUNK];
    __shared__ int lcount;
    __shared__ float partial[4][DIM];

    const float* ind = out + OFF_IND;
    float acc = 0.f;                    // lane d of wave w accumulates dim d
    int total = 0;
    const int w = t >> 6, d = t & 63;

    for (int base = 0; base < N_TOKENS; base += SCAN_CHUNK) {
        if (t == 0) lcount = 0;
        __syncthreads();
#pragma unroll
        for (int j = 0; j < SCAN_CHUNK / 256; ++j) {
            int tok = base + j * 256 + t;
            if (ind[tok] == ef) {
                int p = atomicAdd(&lcount, 1);        // LDS atomic, rare hit
                list[p] = tok;
            }
        }
        __syncthreads();
        int cnt = lcount;
        total += cnt;
        for (int m = w; m < cnt; m += 4)              // wave-strided over matches
            acc += x[(size_t)list[m] * DIM + d];      // 256B coalesced per match
        __syncthreads();                              // before list reuse
    }

    partial[w][d] = acc;
    __syncthreads();
    if (t < DIM) {
        float s = (partial[0][t] + partial[1][t]) + (partial[2][t] + partial[3][t]);
        es[(size_t)e * DIM + t] = s;
        if (t == 0) counts[e] = (float)total;
    }
}

__global__ __launch_bounds__(1024) void vq_final1(
    const float* __restrict__ cluster_size, const float* __restrict__ counts,
    const float* __restrict__ diff_sum, float* __restrict__ out,
    float* __restrict__ n_val)
{
    int e = threadIdx.x;                            // single block of 1024
    float ncs = cluster_size[e] * DECAYF + OMDF * counts[e];
    out[OFF_NCS + e] = ncs;
    __shared__ float red[16];
    float s = ncs;
#pragma unroll
    for (int o = 32; o > 0; o >>= 1) s += __shfl_down(s, o, 64);
    if ((e & 63) == 0) red[e >> 6] = s;
    __syncthreads();
    if (e == 0) {
        float nsum = 0.f;
#pragma unroll
        for (int i = 0; i < 16; ++i) nsum += red[i];
        *n_val = nsum;
        out[OFF_DIFF] = *diff_sum / (float)((size_t)N_TOKENS * DIM);
    }
}

__global__ __launch_bounds__(256) void vq_final2(
    const float* __restrict__ embed_avg, const float* __restrict__ es,
    const float* __restrict__ n_val, float* __restrict__ out)
{
    int i = blockIdx.x * 256 + threadIdx.x;         // 65536, [d][e] flat
    int e = i & 1023, d = i >> 10;
    float nea = embed_avg[i] * DECAYF + OMDF * es[(size_t)e * DIM + d];
    out[OFF_NEA + i] = nea;
    float ncs = out[OFF_NCS + e];
    float nsum = *n_val;
    float cs = (ncs + EPSF) / (nsum + (float)N_EMBED * EPSF) * nsum;
    out[OFF_NE + i] = nea / cs;
}

extern "C" void kernel_launch(void* const* d_in, const int* in_sizes, int n_in,
                              void* d_out, int out_size, void* d_ws, size_t ws_size,
                              hipStream_t stream)
{
    const float* x            = (const float*)d_in[0];
    const float* embed        = (const float*)d_in[1];
    const float* cluster_size = (const float*)d_in[2];
    const float* embed_avg    = (const float*)d_in[3];
    float* out = (float*)d_out;
    float* ws  = (float*)d_ws;

    float* diff_sum = ws + WS_DIFF;
    float* n_val    = ws + WS_NVAL;
    float* counts   = ws + WS_COUNTS;
    float* es       = ws + WS_ES;
    float* embedT   = ws + WS_ET;
    float* cnorm    = ws + WS_CNORM;

    // only diff_sum needs zeroing now (counts/es are written, not accumulated)
    hipMemsetAsync(d_ws, 0, 2 * sizeof(float), stream);

    vq_prep_transpose<<<256, 256, 0, stream>>>(embed, embedT);
    vq_prep_norm<<<4, 256, 0, stream>>>(embedT, cnorm);
    vq_main<<<N_TOKENS / 256, 256, 0, stream>>>(x, embedT, cnorm, out, diff_sum);
    vq_scatter<<<N_EMBED, 256, 0, stream>>>(x, out, counts, es);
    vq_final1<<<1, 1024, 0, stream>>>(cluster_size, counts, diff_sum, out, n_val);
    vq_final2<<<256, 256, 0, stream>>>(embed_avg, es, n_val, out);
}